// Round 10
// baseline (165.845 us; speedup 1.0000x reference)
//
#include <hip/hip_runtime.h>

// LightGCN forward: two gather-scale-scatter-sum propagations.
// Round 10: half-bucket gather blocks. Round-9 profile: gather stage-0 still
// grid-starved (782 blocks = 3/CU, occupancy 52%). Each gather block now
// handles 32 of its bucket's 64 dsts (grid x2, LDS halved to 16.5KB -> 4
// blocks/CU resident), inner loop unrolled x2 (8 edges/iter). scan_tot fused
// into scan_cols via global-cursor atomic base assignment. Bucket-CSR (r7),
// parallel scans (r8), quad-gather (r6), bf16 features (r5) kept.
//
// Sizes: x [100000,128] f32; E0=1.6M edges -> 50000 dsts; E1=0.8M -> 25000.

#define DIMS 128
#define BK   64      // dsts per bucket (partition granularity)
#define BKSH 6
#define CAP2 2048    // LDS-staged edges per HALF bucket (mean 1024, +32 sigma)
#define CH   8192    // edges per partition chunk

__device__ __forceinline__ unsigned bf16_1(float a) {
  unsigned u = __float_as_uint(a);
  return (u + 0x7fffu + ((u >> 16) & 1u)) >> 16;   // RNE
}
__device__ __forceinline__ unsigned pack_bf16(float a, float b) {
  return bf16_1(a) | (bf16_1(b) << 16);
}

// ---------------------------------------- K1: per-chunk bucket histogram + cvt
__global__ __launch_bounds__(256) void hist_cvt(
    const int* __restrict__ dst0, const int* __restrict__ dst1,
    const float* __restrict__ xf, uint4* __restrict__ xbf4,
    int* __restrict__ wgcnt0, int* __restrict__ wgcnt1,
    int E0, int E1, int NB0, int NB1, int NW0, int NW1, long long n8) {
  int b = blockIdx.x;
  if (b < NW0 + NW1) {
    __shared__ int hist[1024];
    const int s1 = (b >= NW0);
    const int w  = s1 ? b - NW0 : b;
    const int E  = s1 ? E1 : E0;
    const int NB = s1 ? NB1 : NB0;
    const int* dst = s1 ? dst1 : dst0;
    int* wgcnt = s1 ? wgcnt1 : wgcnt0;
    for (int i = threadIdx.x; i < NB; i += 256) hist[i] = 0;
    __syncthreads();
    const int beg = w * CH, end = min(beg + CH, E);
    for (int e = beg + threadIdx.x; e < end; e += 256)
      atomicAdd(&hist[dst[e] >> BKSH], 1);
    __syncthreads();
    for (int i = threadIdx.x; i < NB; i += 256)
      wgcnt[w * NB + i] = hist[i];          // [chunk][bucket] -> coalesced
  } else {
    long long t = (long long)(b - NW0 - NW1) * 256 + threadIdx.x;
    if (t < n8) {
      const float4* xf4 = (const float4*)xf;
      float4 v0 = xf4[t * 2], v1 = xf4[t * 2 + 1];
      xbf4[t] = make_uint4(pack_bf16(v0.x, v0.y), pack_bf16(v0.z, v0.w),
                           pack_bf16(v1.x, v1.y), pack_bf16(v1.z, v1.w));
    }
  }
}

// ---------------- K2: per-bucket chunk-prefix scan + global base via atomic.
// One block per bucket; thread w holds chunk w's count (NW <= 256). Bucket
// region order across buckets is irrelevant (regions disjoint), so the base
// comes from an atomicAdd on a per-stage global cursor -> no scan_tot kernel.
__global__ __launch_bounds__(256) void scan_cols(
    int* __restrict__ wgcnt0, int* __restrict__ wgcnt1,
    int* __restrict__ gcur, int2* __restrict__ rg0, int2* __restrict__ rg1,
    int NB0, int NB1, int NW0, int NW1) {
  __shared__ int part[256];
  int b = blockIdx.x;
  const int s1 = (b >= NB0);
  const int i = s1 ? b - NB0 : b;
  int* wgcnt = s1 ? wgcnt1 : wgcnt0;
  int2* rg   = s1 ? rg1 : rg0;
  const int NB = s1 ? NB1 : NB0;
  const int NW = s1 ? NW1 : NW0;
  const int t = threadIdx.x;
  int v = (t < NW) ? wgcnt[t * NB + i] : 0;
  part[t] = v;
  __syncthreads();
  for (int off = 1; off < 256; off <<= 1) {
    int u = (t >= off) ? part[t - off] : 0;
    __syncthreads();
    part[t] += u;
    __syncthreads();
  }
  if (t < NW) wgcnt[t * NB + i] = part[t] - v;   // exclusive (bucket-local)
  if (t == 255) {
    int tot = part[255];
    int base = atomicAdd(&gcur[s1], tot);
    rg[i] = make_int2(base, base + tot);
  }
}

// -------------------------------- K3: chunked partition into bucket regions.
// Payload: x = src; y = (bf16(w) << 16) | (dst & 63).
__global__ __launch_bounds__(512) void partition_k(
    const int* __restrict__ src0, const int* __restrict__ dst0,
    const float* __restrict__ ew0, const int* __restrict__ src1,
    const int* __restrict__ dst1, const float* __restrict__ ew1,
    const int* __restrict__ wgcnt0, const int* __restrict__ wgcnt1,
    const int2* __restrict__ rg0, const int2* __restrict__ rg1,
    int2* __restrict__ payl0, int2* __restrict__ payl1,
    int E0, int E1, int NB0, int NB1, int NW0, int NW1) {
  __shared__ int cur[1024];
  int b = blockIdx.x;
  const int s1 = (b >= NW0);
  const int w  = s1 ? b - NW0 : b;
  const int E  = s1 ? E1 : E0;
  const int NB = s1 ? NB1 : NB0;
  const int* src = s1 ? src1 : src0;
  const int* dst = s1 ? dst1 : dst0;
  const float* ew = s1 ? ew1 : ew0;
  const int* wgcnt = s1 ? wgcnt1 : wgcnt0;
  const int2* rg = s1 ? rg1 : rg0;
  int2* payl = s1 ? payl1 : payl0;
  for (int i = threadIdx.x; i < NB; i += 512)
    cur[i] = rg[i].x + wgcnt[w * NB + i];
  __syncthreads();
  const int beg = w * CH, end = min(beg + CH, E);
  for (int e = beg + threadIdx.x; e < end; e += 512) {
    int d = dst[e];
    int pos = atomicAdd(&cur[d >> BKSH], 1);
    payl[pos] = make_int2(src[e],
                          (int)((bf16_1(ew[e]) << 16) | (unsigned)(d & (BK - 1))));
  }
}

// --------------------- K4/K5: half-bucket gather (one workgroup per 32 dsts).
// Block (bucket b, half): filter-sort the bucket's edges whose dst-low6 falls
// in [half*32, half*32+32) into LDS, then per-dst quad-register-gather:
// lane=(rr=edge slot 0..3, c=16B chunk 0..15), uint4 bf16 row loads, x2
// unrolled (8 edges in flight), shfl_xor combine, one vector store per row.
template <bool OUT_BF16>
__global__ __launch_bounds__(512) void gather_half(
    const uint4* __restrict__ feat, const int2* __restrict__ rg,
    const int2* __restrict__ payl, void* __restrict__ outp, int n_dst) {
  __shared__ int2 lp[CAP2];
  __shared__ int cnt[32], base[32], cnt2[32];
  __shared__ int nf_sh;
  const int b    = blockIdx.x >> 1;
  const int half = blockIdx.x & 1;
  const int tid  = threadIdx.x;
  const int2 r = rg[b];
  const int n = r.y - r.x;
  if (tid < 32) { cnt[tid] = 0; cnt2[tid] = 0; }
  __syncthreads();
  for (int j = tid; j < n; j += 512) {
    int dl = payl[r.x + j].y & (BK - 1);
    if ((dl >> 5) == half) atomicAdd(&cnt[dl & 31], 1);
  }
  __syncthreads();
  if (tid < 32) {                          // wave-0 scan of 32 counts
    int v = cnt[tid];
    int s = v;
    for (int off = 1; off < 32; off <<= 1) {
      int u = __shfl_up(s, off);
      if (tid >= off) s += u;
    }
    base[tid] = s - v;
    if (tid == 31) nf_sh = s;
  }
  __syncthreads();
  const int nf = nf_sh;
  if (nf <= CAP2) {
    for (int j = tid; j < n; j += 512) {
      int2 p = payl[r.x + j];
      int dl = p.y & (BK - 1);
      if ((dl >> 5) == half) {
        int pos = base[dl & 31] + atomicAdd(&cnt2[dl & 31], 1);
        lp[pos] = p;
      }
    }
  }
  __syncthreads();
  const int wave = tid >> 6;               // 0..7
  const int lane = tid & 63;
  const int rr = lane >> 4;
  const int c  = lane & 15;
  for (int dl2 = wave; dl2 < 32; dl2 += 8) {
    const int row = b * BK + half * 32 + dl2;
    if (row >= n_dst) break;               // monotone in dl2 per wave
    float a0 = 0.f, a1 = 0.f, a2 = 0.f, a3 = 0.f;
    float a4 = 0.f, a5 = 0.f, a6 = 0.f, a7 = 0.f;
    if (nf <= CAP2) {
      const int bg = base[dl2];
      const int en = bg + cnt[dl2];
      for (int j = bg; j < en; j += 8) {   // 8 edges/iter: 2 quads in flight
        int jj0 = j + rr;
        int jj1 = j + 4 + rr;
        int2 p0 = (jj0 < en) ? lp[jj0] : make_int2(0, 0);
        int2 p1 = (jj1 < en) ? lp[jj1] : make_int2(0, 0);
        float w0 = __uint_as_float((unsigned)p0.y & 0xffff0000u);
        float w1 = __uint_as_float((unsigned)p1.y & 0xffff0000u);
        uint4 u0 = feat[(size_t)p0.x * 16 + c];
        uint4 u1 = feat[(size_t)p1.x * 16 + c];
        a0 += __uint_as_float(u0.x << 16) * w0;
        a1 += __uint_as_float(u0.x & 0xffff0000u) * w0;
        a2 += __uint_as_float(u0.y << 16) * w0;
        a3 += __uint_as_float(u0.y & 0xffff0000u) * w0;
        a4 += __uint_as_float(u0.z << 16) * w0;
        a5 += __uint_as_float(u0.z & 0xffff0000u) * w0;
        a6 += __uint_as_float(u0.w << 16) * w0;
        a7 += __uint_as_float(u0.w & 0xffff0000u) * w0;
        a0 += __uint_as_float(u1.x << 16) * w1;
        a1 += __uint_as_float(u1.x & 0xffff0000u) * w1;
        a2 += __uint_as_float(u1.y << 16) * w1;
        a3 += __uint_as_float(u1.y & 0xffff0000u) * w1;
        a4 += __uint_as_float(u1.z << 16) * w1;
        a5 += __uint_as_float(u1.z & 0xffff0000u) * w1;
        a6 += __uint_as_float(u1.w << 16) * w1;
        a7 += __uint_as_float(u1.w & 0xffff0000u) * w1;
      }
    } else {
      // Overflow fallback (statistically unreachable): direct global walk.
      const int want = half * 32 + dl2;
      for (int j = 0; j < n; j += 4) {
        int jj = j + rr;
        int2 p = (jj < n) ? payl[r.x + jj] : make_int2(0, 0);
        bool mine = (jj < n) && ((p.y & (BK - 1)) == want);
        float wgt = mine ? __uint_as_float((unsigned)p.y & 0xffff0000u) : 0.f;
        uint4 u = feat[(size_t)p.x * 16 + c];
        a0 += __uint_as_float(u.x << 16) * wgt;
        a1 += __uint_as_float(u.x & 0xffff0000u) * wgt;
        a2 += __uint_as_float(u.y << 16) * wgt;
        a3 += __uint_as_float(u.y & 0xffff0000u) * wgt;
        a4 += __uint_as_float(u.z << 16) * wgt;
        a5 += __uint_as_float(u.z & 0xffff0000u) * wgt;
        a6 += __uint_as_float(u.w << 16) * wgt;
        a7 += __uint_as_float(u.w & 0xffff0000u) * wgt;
      }
    }
    a0 += __shfl_xor(a0, 16); a0 += __shfl_xor(a0, 32);
    a1 += __shfl_xor(a1, 16); a1 += __shfl_xor(a1, 32);
    a2 += __shfl_xor(a2, 16); a2 += __shfl_xor(a2, 32);
    a3 += __shfl_xor(a3, 16); a3 += __shfl_xor(a3, 32);
    a4 += __shfl_xor(a4, 16); a4 += __shfl_xor(a4, 32);
    a5 += __shfl_xor(a5, 16); a5 += __shfl_xor(a5, 32);
    a6 += __shfl_xor(a6, 16); a6 += __shfl_xor(a6, 32);
    a7 += __shfl_xor(a7, 16); a7 += __shfl_xor(a7, 32);
    if (OUT_BF16) {
      if (rr == 0) {
        ((uint4*)outp)[(size_t)row * 16 + c] =
            make_uint4(pack_bf16(a0, a1), pack_bf16(a2, a3),
                       pack_bf16(a4, a5), pack_bf16(a6, a7));
      }
    } else {
      if (rr < 2) {
        ((float4*)outp)[(size_t)row * 32 + c * 2 + rr] =
            (rr == 0) ? make_float4(a0, a1, a2, a3)
                      : make_float4(a4, a5, a6, a7);
      }
    }
  }
}

// ------------------------------------------------- fallback (round-1 path)
#define COLG 32
__global__ __launch_bounds__(256) void prop_atomic(
    const float* __restrict__ x, const int* __restrict__ src,
    const int* __restrict__ dst, const float* __restrict__ ew,
    float* __restrict__ out, int E) {
  long long idx = (long long)blockIdx.x * blockDim.x + threadIdx.x;
  long long total = (long long)E * COLG;
  if (idx >= total) return;
  int e = (int)(idx >> 5);
  int cg = (int)(idx & 31);
  int s = src[e];
  int d = dst[e];
  float w = ew[e];
  const float4 v = *reinterpret_cast<const float4*>(x + (size_t)s * DIMS + cg * 4);
  float* o = out + (size_t)d * DIMS + cg * 4;
  atomicAdd(o + 0, v.x * w);
  atomicAdd(o + 1, v.y * w);
  atomicAdd(o + 2, v.z * w);
  atomicAdd(o + 3, v.w * w);
}

// --------------------------------------------------------------- launcher

static inline size_t align_up(size_t v, size_t a) { return (v + a - 1) / a * a; }

extern "C" void kernel_launch(void* const* d_in, const int* in_sizes, int n_in,
                              void* d_out, int out_size, void* d_ws, size_t ws_size,
                              hipStream_t stream) {
  const float* x    = (const float*)d_in[0];
  const int*   src0 = (const int*)d_in[1];
  const int*   dst0 = (const int*)d_in[2];
  const float* ew0  = (const float*)d_in[3];
  const int*   src1 = (const int*)d_in[4];
  const int*   dst1 = (const int*)d_in[5];
  const float* ew1  = (const float*)d_in[6];

  const int N_SRC0 = in_sizes[0] / DIMS;  // 100000
  const int E0 = in_sizes[1];             // 1600000
  const int E1 = in_sizes[4];             // 800000
  const int N_DST0 = 50000;
  const int N_DST1 = 25000;

  const int NB0 = (N_DST0 + BK - 1) / BK;   // 782
  const int NB1 = (N_DST1 + BK - 1) / BK;   // 391
  const int NW0 = (E0 + CH - 1) / CH;       // 196
  const int NW1 = (E1 + CH - 1) / CH;       // 98

  float* out = (float*)d_out;

  // --- workspace layout ---
  char* ws = (char*)d_ws;
  size_t off = 0;
  uint4* xb    = (uint4*)(ws + off); off = align_up(off + (size_t)N_SRC0 * 64 * 4, 16);
  uint4* hb    = (uint4*)(ws + off); off = align_up(off + (size_t)N_DST0 * 64 * 4, 16);
  int* wgcnt0  = (int*)(ws + off);   off = align_up(off + (size_t)NW0 * NB0 * 4, 16);
  int* wgcnt1  = (int*)(ws + off);   off = align_up(off + (size_t)NW1 * NB1 * 4, 16);
  int* gcur    = (int*)(ws + off);   off = align_up(off + 2 * 4, 16);
  int2* rg0    = (int2*)(ws + off);  off = align_up(off + (size_t)NB0 * 8, 16);
  int2* rg1    = (int2*)(ws + off);  off = align_up(off + (size_t)NB1 * 8, 16);
  int2* payl0  = (int2*)(ws + off);  off = align_up(off + (size_t)E0 * 8, 16);
  int2* payl1  = (int2*)(ws + off);  off = align_up(off + (size_t)E1 * 8, 16);
  const size_t needed = off;

  if (ws_size < needed) {
    float* h = (float*)d_ws;
    hipMemsetAsync(h, 0, (size_t)N_DST0 * DIMS * 4, stream);
    hipMemsetAsync(out, 0, (size_t)N_DST1 * DIMS * 4, stream);
    long long t0 = (long long)E0 * COLG;
    prop_atomic<<<(int)((t0 + 255) / 256), 256, 0, stream>>>(x, src0, dst0, ew0, h, E0);
    long long t1 = (long long)E1 * COLG;
    prop_atomic<<<(int)((t1 + 255) / 256), 256, 0, stream>>>(h, src1, dst1, ew1, out, E1);
    return;
  }

  const long long n8 = (long long)N_SRC0 * 16;   // uint4 words in xb
  const int cvtBlocks = (int)((n8 + 255) / 256);

  // 0. zero the two payload cursors
  hipMemsetAsync(gcur, 0, 2 * 4, stream);

  // K1: bucket histograms (both stages) + f32->bf16 conversion
  hist_cvt<<<NW0 + NW1 + cvtBlocks, 256, 0, stream>>>(
      dst0, dst1, x, xb, wgcnt0, wgcnt1, E0, E1, NB0, NB1, NW0, NW1, n8);

  // K2: per-bucket chunk-prefix scan + atomic base assignment (both stages)
  scan_cols<<<NB0 + NB1, 256, 0, stream>>>(wgcnt0, wgcnt1, gcur, rg0, rg1,
                                           NB0, NB1, NW0, NW1);

  // K3: partition edges into bucket regions (both stages)
  partition_k<<<NW0 + NW1, 512, 0, stream>>>(
      src0, dst0, ew0, src1, dst1, ew1, wgcnt0, wgcnt1, rg0, rg1,
      payl0, payl1, E0, E1, NB0, NB1, NW0, NW1);

  // K4: stage-1 gather: hb[dst0] += xb[src0] * ew0  (bf16 out)
  gather_half<true><<<2 * NB0, 512, 0, stream>>>(xb, rg0, payl0, (void*)hb, N_DST0);

  // K5: stage-2 gather: out[dst1] += hb[src1] * ew1  (f32 out)
  gather_half<false><<<2 * NB1, 512, 0, stream>>>(hb, rg1, payl1, (void*)out, N_DST1);
}